// Round 15
// baseline (434.095 us; speedup 1.0000x reference)
//
#include <hip/hip_runtime.h>

#define N_IN   16384
#define N_OUT  16384
#define KSZ    9
#define CIN    32
#define COUT   32
#define BC     64
#define NCB    256         // coarse buckets = io >> 6  (64 n each)
#define CHA    4096        // bin chunk
#define ECAP_A 8192        // sivA region per coarse bucket (mean 5859, +30 sigma)
#define ROWS   144         // 9 k * 16 n per fine slice
#define XSTR   68          // sxk row stride: %32==4 -> max 4-way on b128, 16B-aligned
#define SCAP   2048        // slist cap per fine slice (mean 1465, +15 sigma)
#define GRID   1024        // == 256 CU * 4 blocks/CU (39.3 KB LDS, <=64 VGPR)

union SH {
    struct { int cnt[NCB]; int cntE[NCB]; int gbase[NCB]; int cursor[NCB];
             float2 slist[CHA]; } bin;                       // 36.9 KB
    struct { float tile[64 * 65]; } xqp;                     // 16.6 KB
    struct { __align__(16) float sxk[80 * XSTR]; float2 slist[SCAP];
             int rowStart[ROWS + 1]; int cursor[ROWS]; int mcur; } fu;  // 39.3 KB
};

// ---------------------------------------------------------------------------
__global__ __launch_bounds__(512, 8) void k_all(
        const float* __restrict__ x, const float* __restrict__ qw,
        const float* __restrict__ vals, const float* __restrict__ w,
        const float* __restrict__ bias, const int* __restrict__ ik,
        const int* __restrict__ io, const int* __restrict__ ii,
        float* __restrict__ xq, float2* __restrict__ sivA,
        int* __restrict__ gcntA, int* __restrict__ done,
        float* __restrict__ wT, float* __restrict__ out, int nnz, int nchA) {
    __shared__ SH sh;
    const int tid  = threadIdx.x;
    const int lane = tid & 63;
    const int wv   = __builtin_amdgcn_readfirstlane(tid >> 6);
    const int bid  = blockIdx.x;

    // ===================== phase 1 =====================
    if (bid < nchA) {
        // ---- bin one 4096-entry chunk into 256 coarse buckets
        if (tid < NCB) sh.bin.cnt[tid] = 0;
        __syncthreads();
        const int base = bid * CHA;
        const int e0   = base + tid * 8;
        float vv[8]; int pk[8]; int bk[8]; bool hv[8];
        if (e0 + 8 <= nnz) {
            int4 a0 = *(const int4*)(io + e0),  a1 = *(const int4*)(io + e0 + 4);
            int4 b0 = *(const int4*)(ii + e0),  b1 = *(const int4*)(ii + e0 + 4);
            int4 k0 = *(const int4*)(ik + e0),  k1 = *(const int4*)(ik + e0 + 4);
            float4 d0 = *(const float4*)(vals + e0), d1 = *(const float4*)(vals + e0 + 4);
            int ov[8] = {a0.x, a0.y, a0.z, a0.w, a1.x, a1.y, a1.z, a1.w};
            int iv[8] = {b0.x, b0.y, b0.z, b0.w, b1.x, b1.y, b1.z, b1.w};
            int kv[8] = {k0.x, k0.y, k0.z, k0.w, k1.x, k1.y, k1.z, k1.w};
            float dv[8] = {d0.x, d0.y, d0.z, d0.w, d1.x, d1.y, d1.z, d1.w};
#pragma unroll
            for (int j = 0; j < 8; ++j) {
                hv[j] = true;
                bk[j] = ov[j] >> 6;
                pk[j] = (int)(((unsigned)(ov[j] >> 4) << 22)) | (iv[j] << 8) | (kv[j] * 16 + (ov[j] & 15));
                vv[j] = dv[j];
            }
        } else {
#pragma unroll
            for (int j = 0; j < 8; ++j) {
                int e = e0 + j;
                hv[j] = (e < nnz);
                if (hv[j]) {
                    int o = io[e];
                    bk[j] = o >> 6;
                    pk[j] = (int)(((unsigned)(o >> 4) << 22)) | (ii[e] << 8) | (ik[e] * 16 + (o & 15));
                    vv[j] = vals[e];
                } else { bk[j] = 0; pk[j] = 0; vv[j] = 0.f; }
            }
        }
#pragma unroll
        for (int j = 0; j < 8; ++j) if (hv[j]) atomicAdd(&sh.bin.cnt[bk[j]], 1);
        __syncthreads();
        if (tid < NCB) {
            int cv = sh.bin.cnt[tid];
            sh.bin.gbase[tid] = tid * ECAP_A + (cv ? atomicAdd(&gcntA[tid], cv) : 0);
        }
        if (tid < 64) {
            int carry = 0;
#pragma unroll
            for (int seg = 0; seg < 4; ++seg) {
                int idx = seg * 64 + tid;
                int v = sh.bin.cnt[idx];
                int orig = v;
#pragma unroll
                for (int off = 1; off < 64; off <<= 1) {
                    int u = __shfl_up(v, off);
                    if (tid >= off) v += u;
                }
                sh.bin.cntE[idx]   = carry + v - orig;
                sh.bin.cursor[idx] = carry + v - orig;
                carry += __shfl(v, 63);
            }
        }
        __syncthreads();
#pragma unroll
        for (int j = 0; j < 8; ++j) {
            if (hv[j]) {
                int pos = atomicAdd(&sh.bin.cursor[bk[j]], 1);
                sh.bin.slist[pos] = make_float2(vv[j], __int_as_float(pk[j]));
            }
        }
        __syncthreads();
        const int m = min(nnz - base, CHA);
        for (int p = tid; p < m; p += 512) {
            float2 f2 = sh.bin.slist[p];
            int cb = (int)((unsigned)__float_as_int(f2.y) >> 24);
            int dest = sh.bin.gbase[cb] + (p - sh.bin.cntE[cb]);
            if (dest < (cb + 1) * ECAP_A) sivA[dest] = f2;
        }
    } else if (bid < nchA + 256) {
        // ---- xq transpose tile: xq[in][bc] = x[bc][in] * qw[in]
        const int in0 = (bid - nchA) * 64;
#pragma unroll
        for (int i = 0; i < 8; ++i) {
            int idx = tid + i * 512;
            int bcl = idx >> 6, inl = idx & 63;
            sh.xqp.tile[bcl * 65 + inl] = x[bcl * N_IN + in0 + inl];
        }
        __syncthreads();
#pragma unroll
        for (int i = 0; i < 8; ++i) {
            int idx = tid + i * 512;
            int inl = idx >> 6, bcl = idx & 63;
            xq[(size_t)(in0 + inl) * BC + bcl] = sh.xqp.tile[bcl * 65 + inl] * qw[in0 + inl];
        }
    } else if (bid == nchA + 256) {
        for (int i = tid; i < COUT * CIN * KSZ; i += 512) {
            int o = i / (CIN * KSZ);
            int r = i - o * (CIN * KSZ);
            int c = r / KSZ;
            int k = r - c * KSZ;
            wT[((k * 8 + (o >> 2)) * 32 + c) * 4 + (o & 3)] = w[i];
        }
    }

    // ===================== device barrier (all 1024 blocks co-resident) =====
    __syncthreads();
    if (tid == 0) {
        __threadfence();                       // release sivA/xq/wT/gcntA
        atomicAdd(done, 1);
        while (atomicAdd(done, 0) < GRID) __builtin_amdgcn_s_sleep(8);
    }
    __syncthreads();
    __threadfence();                           // acquire

    // ===================== phase 2: fused slice f = bid =====================
    const unsigned f = (unsigned)bid;
    if (tid < ROWS) sh.fu.rowStart[tid] = 0;
    if (tid == 0) sh.fu.mcur = 0;
    __syncthreads();

    const int cb = (int)(f >> 2);
    const int mA = min(gcntA[cb], ECAP_A);
    const float2* src = sivA + (size_t)cb * ECAP_A;
    float2* tmp = (float2*)sh.fu.sxk;
    const int iters = (mA + 511) >> 9;
    for (int it = 0; it < iters; ++it) {
        int i = (it << 9) + tid;
        bool inr = (i < mA);
        float2 v = inr ? src[i] : make_float2(0.f, __int_as_float(-1));
        bool match = inr && (((unsigned)__float_as_int(v.y) >> 22) == f);
        unsigned long long mask = __ballot(match);
        if (mask) {
            int ldr    = (int)(__ffsll((unsigned long long)mask) - 1);
            int prefix = __popcll(mask & ((1ULL << lane) - 1ULL));
            int base2  = 0;
            if (lane == ldr) base2 = atomicAdd(&sh.fu.mcur, __popcll(mask));
            base2 = __shfl(base2, ldr);
            if (match) {
                int pos = base2 + prefix;
                if (pos < SCAP) {
                    tmp[pos] = v;
                    atomicAdd(&sh.fu.rowStart[__float_as_int(v.y) & 0xFF], 1);
                }
            }
        }
    }
    __syncthreads();
    const int m2 = min(sh.fu.mcur, SCAP);
    if (wv == 0) {   // exclusive scan over 144 counts
        int carry = 0;
#pragma unroll
        for (int i0 = 0; i0 < 192; i0 += 64) {
            int idx = i0 + lane;
            int v = (idx < ROWS) ? sh.fu.rowStart[idx] : 0;
            int orig = v;
#pragma unroll
            for (int off = 1; off < 64; off <<= 1) {
                int u = __shfl_up(v, off);
                if (lane >= off) v += u;
            }
            if (idx < ROWS) {
                int excl = carry + v - orig;
                sh.fu.rowStart[idx] = excl;
                sh.fu.cursor[idx]   = excl;
            }
            carry += __shfl(v, 63);
        }
        if (lane == 0) sh.fu.rowStart[ROWS] = carry;
    }
    __syncthreads();
    // LDS->LDS scatter; strip row bits so gather needs only v_add
    for (int i = tid; i < m2; i += 512) {
        float2 v = tmp[i];
        int p = __float_as_int(v.y);
        int pos = atomicAdd(&sh.fu.cursor[p & 0xFF], 1);
        sh.fu.slist[pos] = make_float2(v.x, __int_as_float(p & 0x3FFF00));
    }
    __syncthreads();   // tmp reads complete before sxk zeroing

    const char* xqb   = (const char*)xq;
    const int   lane4 = lane * 4;
    const int   h     = lane >> 4;
    const int   nl    = lane & 15;
    float acc[4] = {0.f, 0.f, 0.f, 0.f};

#pragma unroll
    for (int ph = 0; ph < 2; ++ph) {
        const int rbase = ph ? 80 : 0;
        const int rend  = ph ? 144 : 80;
        const int nrows = rend - rbase;
        for (int i = tid; i < nrows * XSTR; i += 512) sh.fu.sxk[i] = 0.f;
        __syncthreads();
        for (int r = rbase + wv; r < rend; r += 8) {
            const int a = sh.fu.rowStart[r], b = sh.fu.rowStart[r + 1];
            if (a >= b) continue;
            float acc0 = 0.f, acc1 = 0.f, acc2 = 0.f, acc3 = 0.f;
            int i = a;
            for (; i + 7 < b; i += 8) {
                float2 v0 = sh.fu.slist[i],     v1 = sh.fu.slist[i + 1];
                float2 v2 = sh.fu.slist[i + 2], v3 = sh.fu.slist[i + 3];
                float2 v4 = sh.fu.slist[i + 4], v5 = sh.fu.slist[i + 5];
                float2 v6 = sh.fu.slist[i + 6], v7 = sh.fu.slist[i + 7];
                acc0 += *(const float*)(xqb + (__float_as_int(v0.y) + lane4)) * v0.x;
                acc1 += *(const float*)(xqb + (__float_as_int(v1.y) + lane4)) * v1.x;
                acc2 += *(const float*)(xqb + (__float_as_int(v2.y) + lane4)) * v2.x;
                acc3 += *(const float*)(xqb + (__float_as_int(v3.y) + lane4)) * v3.x;
                acc0 += *(const float*)(xqb + (__float_as_int(v4.y) + lane4)) * v4.x;
                acc1 += *(const float*)(xqb + (__float_as_int(v5.y) + lane4)) * v5.x;
                acc2 += *(const float*)(xqb + (__float_as_int(v6.y) + lane4)) * v6.x;
                acc3 += *(const float*)(xqb + (__float_as_int(v7.y) + lane4)) * v7.x;
            }
            for (; i + 3 < b; i += 4) {
                float2 v0 = sh.fu.slist[i],     v1 = sh.fu.slist[i + 1];
                float2 v2 = sh.fu.slist[i + 2], v3 = sh.fu.slist[i + 3];
                acc0 += *(const float*)(xqb + (__float_as_int(v0.y) + lane4)) * v0.x;
                acc1 += *(const float*)(xqb + (__float_as_int(v1.y) + lane4)) * v1.x;
                acc2 += *(const float*)(xqb + (__float_as_int(v2.y) + lane4)) * v2.x;
                acc3 += *(const float*)(xqb + (__float_as_int(v3.y) + lane4)) * v3.x;
            }
            for (; i < b; ++i) {
                float2 v = sh.fu.slist[i];
                acc0 += *(const float*)(xqb + (__float_as_int(v.y) + lane4)) * v.x;
            }
            sh.fu.sxk[(r - rbase) * XSTR + lane] = (acc0 + acc1) + (acc2 + acc3);
        }
        __syncthreads();
        if (lane < 32) {
            const int kbase = ph ? 5 : 0;
            const int kcnt  = ph ? 4 : 5;
            for (int kk = 0; kk < kcnt; ++kk) {
                const float* xr = &sh.fu.sxk[(kk * 16 + nl) * XSTR + h * 32];
                const float* wp = &wT[((kbase + kk) * 8 + wv) * 128];   // uniform -> s_load
#pragma unroll
                for (int c4 = 0; c4 < 8; ++c4) {
                    float4 xv = *(const float4*)&xr[c4 * 4];
#pragma unroll
                    for (int cc = 0; cc < 4; ++cc) {
                        float xval = (&xv.x)[cc];
#pragma unroll
                        for (int j = 0; j < 4; ++j)
                            acc[j] += xval * wp[(c4 * 4 + cc) * 4 + j];
                    }
                }
            }
        }
        __syncthreads();
    }

    if (lane < 32) {
        const int n0 = (int)f * 16;
#pragma unroll
        for (int j = 0; j < 4; ++j) {
            int o = wv * 4 + j;
            out[((size_t)h * COUT + o) * N_OUT + n0 + nl] = acc[j] + bias[o];
        }
    }
}

// ---------------------------------------------------------------------------
extern "C" void kernel_launch(void* const* d_in, const int* in_sizes, int n_in,
                              void* d_out, int out_size, void* d_ws, size_t ws_size,
                              hipStream_t stream) {
    const float* x    = (const float*)d_in[0];
    const float* qw   = (const float*)d_in[1];
    const float* vals = (const float*)d_in[2];
    const float* w    = (const float*)d_in[3];
    const float* bias = (const float*)d_in[4];
    const int*   ik   = (const int*)d_in[5];
    const int*   io   = (const int*)d_in[6];
    const int*   ii   = (const int*)d_in[7];
    const int    nnz  = in_sizes[2];
    const int    nchA = (nnz + CHA - 1) / CHA;

    char* ws = (char*)d_ws;
    float*  xq    = (float*)ws;  ws += (size_t)N_IN * BC * 4;        // 4 MB
    float2* sivA  = (float2*)ws; ws += (size_t)NCB * ECAP_A * 8;     // 16.78 MB
    int*    gcntA = (int*)ws;    ws += NCB * 4;
    int*    done  = (int*)ws;    ws += 4;
    float*  wT    = (float*)ws;  ws += (size_t)COUT * CIN * KSZ * 4;

    hipMemsetAsync(gcntA, 0, (NCB + 1) * sizeof(int), stream);   // gcntA + done
    k_all<<<GRID, 512, 0, stream>>>(x, qw, vals, w, bias, ik, io, ii,
                                    xq, sivA, gcntA, done, wT,
                                    (float*)d_out, nnz, nchA);
}

// Round 16
// 371.523 us; speedup vs baseline: 1.1684x; 1.1684x over previous
//
#include <hip/hip_runtime.h>

#define N_IN   16384
#define N_OUT  16384
#define KSZ    9
#define CIN    32
#define COUT   32
#define BC     64
#define NCB    256         // coarse buckets = io >> 6  (64 n each)
#define CHA    4096        // bin chunk
#define ECAP_A 8192        // sivA region per coarse bucket (mean 5859, +30 sigma)
#define ROWS   144         // 9 k * 16 n per fine slice
#define XSTR   68          // sxk row stride: %32==4 -> max 4-way on b128, 16B-aligned
#define SCAP   2048        // slist cap per fine slice (mean 1465, +15 sigma)
#define GRID   1024        // == 256 CU * 4 blocks/CU (39.3 KB LDS, <=64 VGPR)

union SH {
    struct { int cnt[NCB]; int cntE[NCB]; int gbase[NCB]; int cursor[NCB];
             float2 slist[CHA]; } bin;                       // 36.9 KB
    struct { float tile[64 * 65]; } xqp;                     // 16.6 KB
    struct { __align__(16) float sxk[80 * XSTR]; float2 slist[SCAP];
             int rowStart[ROWS + 1]; int cursor[ROWS]; int mcur; } fu;  // 39.3 KB
};

// ---------------------------------------------------------------------------
__global__ __launch_bounds__(512, 8) void k_all(
        const float* __restrict__ x, const float* __restrict__ qw,
        const float* __restrict__ vals, const float* __restrict__ w,
        const float* __restrict__ bias, const int* __restrict__ ik,
        const int* __restrict__ io, const int* __restrict__ ii,
        float* __restrict__ xq, float2* __restrict__ sivA,
        int* __restrict__ gcntA, int* __restrict__ done,
        float* __restrict__ wT, float* __restrict__ out, int nnz, int nchA) {
    __shared__ SH sh;
    const int tid  = threadIdx.x;
    const int lane = tid & 63;
    const int wv   = __builtin_amdgcn_readfirstlane(tid >> 6);
    const int bid  = blockIdx.x;

    // ===================== phase 1 =====================
    if (bid < nchA) {
        // ---- bin one 4096-entry chunk into 256 coarse buckets
        if (tid < NCB) sh.bin.cnt[tid] = 0;
        __syncthreads();
        const int base = bid * CHA;
        const int e0   = base + tid * 8;
        float vv[8]; int pk[8]; int bk[8]; bool hv[8];
        if (e0 + 8 <= nnz) {
            int4 a0 = *(const int4*)(io + e0),  a1 = *(const int4*)(io + e0 + 4);
            int4 b0 = *(const int4*)(ii + e0),  b1 = *(const int4*)(ii + e0 + 4);
            int4 k0 = *(const int4*)(ik + e0),  k1 = *(const int4*)(ik + e0 + 4);
            float4 d0 = *(const float4*)(vals + e0), d1 = *(const float4*)(vals + e0 + 4);
            int ov[8] = {a0.x, a0.y, a0.z, a0.w, a1.x, a1.y, a1.z, a1.w};
            int iv[8] = {b0.x, b0.y, b0.z, b0.w, b1.x, b1.y, b1.z, b1.w};
            int kv[8] = {k0.x, k0.y, k0.z, k0.w, k1.x, k1.y, k1.z, k1.w};
            float dv[8] = {d0.x, d0.y, d0.z, d0.w, d1.x, d1.y, d1.z, d1.w};
#pragma unroll
            for (int j = 0; j < 8; ++j) {
                hv[j] = true;
                bk[j] = ov[j] >> 6;
                pk[j] = (int)(((unsigned)(ov[j] >> 4) << 22)) | (iv[j] << 8) | (kv[j] * 16 + (ov[j] & 15));
                vv[j] = dv[j];
            }
        } else {
#pragma unroll
            for (int j = 0; j < 8; ++j) {
                int e = e0 + j;
                hv[j] = (e < nnz);
                if (hv[j]) {
                    int o = io[e];
                    bk[j] = o >> 6;
                    pk[j] = (int)(((unsigned)(o >> 4) << 22)) | (ii[e] << 8) | (ik[e] * 16 + (o & 15));
                    vv[j] = vals[e];
                } else { bk[j] = 0; pk[j] = 0; vv[j] = 0.f; }
            }
        }
#pragma unroll
        for (int j = 0; j < 8; ++j) if (hv[j]) atomicAdd(&sh.bin.cnt[bk[j]], 1);
        __syncthreads();
        if (tid < NCB) {
            int cv = sh.bin.cnt[tid];
            sh.bin.gbase[tid] = tid * ECAP_A + (cv ? atomicAdd(&gcntA[tid], cv) : 0);
        }
        if (tid < 64) {
            int carry = 0;
#pragma unroll
            for (int seg = 0; seg < 4; ++seg) {
                int idx = seg * 64 + tid;
                int v = sh.bin.cnt[idx];
                int orig = v;
#pragma unroll
                for (int off = 1; off < 64; off <<= 1) {
                    int u = __shfl_up(v, off);
                    if (tid >= off) v += u;
                }
                sh.bin.cntE[idx]   = carry + v - orig;
                sh.bin.cursor[idx] = carry + v - orig;
                carry += __shfl(v, 63);
            }
        }
        __syncthreads();
#pragma unroll
        for (int j = 0; j < 8; ++j) {
            if (hv[j]) {
                int pos = atomicAdd(&sh.bin.cursor[bk[j]], 1);
                sh.bin.slist[pos] = make_float2(vv[j], __int_as_float(pk[j]));
            }
        }
        __syncthreads();
        const int m = min(nnz - base, CHA);
        for (int p = tid; p < m; p += 512) {
            float2 f2 = sh.bin.slist[p];
            int cb = (int)((unsigned)__float_as_int(f2.y) >> 24);
            int dest = sh.bin.gbase[cb] + (p - sh.bin.cntE[cb]);
            if (dest < (cb + 1) * ECAP_A) sivA[dest] = f2;
        }
    } else if (bid < nchA + 256) {
        // ---- xq transpose tile: xq[in][bc] = x[bc][in] * qw[in]
        const int in0 = (bid - nchA) * 64;
#pragma unroll
        for (int i = 0; i < 8; ++i) {
            int idx = tid + i * 512;
            int bcl = idx >> 6, inl = idx & 63;
            sh.xqp.tile[bcl * 65 + inl] = x[bcl * N_IN + in0 + inl];
        }
        __syncthreads();
#pragma unroll
        for (int i = 0; i < 8; ++i) {
            int idx = tid + i * 512;
            int inl = idx >> 6, bcl = idx & 63;
            xq[(size_t)(in0 + inl) * BC + bcl] = sh.xqp.tile[bcl * 65 + inl] * qw[in0 + inl];
        }
    } else if (bid == nchA + 256) {
        for (int i = tid; i < COUT * CIN * KSZ; i += 512) {
            int o = i / (CIN * KSZ);
            int r = i - o * (CIN * KSZ);
            int c = r / KSZ;
            int k = r - c * KSZ;
            wT[((k * 8 + (o >> 2)) * 32 + c) * 4 + (o & 3)] = w[i];
        }
    }

    // ===================== device barrier (all 1024 blocks co-resident) =====
    // arrival = one release RMW per block; spin = coherent LOADS only (no RMW
    // write-traffic storm -- R15's atomicAdd(done,0) spin cost ~250us).
    __syncthreads();
    if (tid == 0) {
        __hip_atomic_fetch_add(done, 1, __ATOMIC_RELEASE, __HIP_MEMORY_SCOPE_AGENT);
        while (__hip_atomic_load(done, __ATOMIC_ACQUIRE, __HIP_MEMORY_SCOPE_AGENT) < GRID)
            __builtin_amdgcn_s_sleep(4);
    }
    __syncthreads();

    // ===================== phase 2: fused slice f = bid =====================
    const unsigned f = (unsigned)bid;
    if (tid < ROWS) sh.fu.rowStart[tid] = 0;
    if (tid == 0) sh.fu.mcur = 0;
    __syncthreads();

    const int cb = (int)(f >> 2);
    const int mA = min(gcntA[cb], ECAP_A);
    const float2* src = sivA + (size_t)cb * ECAP_A;
    float2* tmp = (float2*)sh.fu.sxk;
    const int iters = (mA + 511) >> 9;
    for (int it = 0; it < iters; ++it) {
        int i = (it << 9) + tid;
        bool inr = (i < mA);
        float2 v = inr ? src[i] : make_float2(0.f, __int_as_float(-1));
        bool match = inr && (((unsigned)__float_as_int(v.y) >> 22) == f);
        unsigned long long mask = __ballot(match);
        if (mask) {
            int ldr    = (int)(__ffsll((unsigned long long)mask) - 1);
            int prefix = __popcll(mask & ((1ULL << lane) - 1ULL));
            int base2  = 0;
            if (lane == ldr) base2 = atomicAdd(&sh.fu.mcur, __popcll(mask));
            base2 = __shfl(base2, ldr);
            if (match) {
                int pos = base2 + prefix;
                if (pos < SCAP) {
                    tmp[pos] = v;
                    atomicAdd(&sh.fu.rowStart[__float_as_int(v.y) & 0xFF], 1);
                }
            }
        }
    }
    __syncthreads();
    const int m2 = min(sh.fu.mcur, SCAP);
    if (wv == 0) {   // exclusive scan over 144 counts
        int carry = 0;
#pragma unroll
        for (int i0 = 0; i0 < 192; i0 += 64) {
            int idx = i0 + lane;
            int v = (idx < ROWS) ? sh.fu.rowStart[idx] : 0;
            int orig = v;
#pragma unroll
            for (int off = 1; off < 64; off <<= 1) {
                int u = __shfl_up(v, off);
                if (lane >= off) v += u;
            }
            if (idx < ROWS) {
                int excl = carry + v - orig;
                sh.fu.rowStart[idx] = excl;
                sh.fu.cursor[idx]   = excl;
            }
            carry += __shfl(v, 63);
        }
        if (lane == 0) sh.fu.rowStart[ROWS] = carry;
    }
    __syncthreads();
    // LDS->LDS scatter; strip row bits so gather needs only v_add
    for (int i = tid; i < m2; i += 512) {
        float2 v = tmp[i];
        int p = __float_as_int(v.y);
        int pos = atomicAdd(&sh.fu.cursor[p & 0xFF], 1);
        sh.fu.slist[pos] = make_float2(v.x, __int_as_float(p & 0x3FFF00));
    }
    __syncthreads();   // tmp reads complete before sxk zeroing

    const char* xqb   = (const char*)xq;
    const int   lane4 = lane * 4;
    const int   h     = lane >> 4;
    const int   nl    = lane & 15;
    float acc[4] = {0.f, 0.f, 0.f, 0.f};

#pragma unroll
    for (int ph = 0; ph < 2; ++ph) {
        const int rbase = ph ? 80 : 0;
        const int rend  = ph ? 144 : 80;
        const int nrows = rend - rbase;
        for (int i = tid; i < nrows * XSTR; i += 512) sh.fu.sxk[i] = 0.f;
        __syncthreads();
        for (int r = rbase + wv; r < rend; r += 8) {
            const int a = sh.fu.rowStart[r], b = sh.fu.rowStart[r + 1];
            if (a >= b) continue;
            float acc0 = 0.f, acc1 = 0.f, acc2 = 0.f, acc3 = 0.f;
            int i = a;
            for (; i + 7 < b; i += 8) {
                float2 v0 = sh.fu.slist[i],     v1 = sh.fu.slist[i + 1];
                float2 v2 = sh.fu.slist[i + 2], v3 = sh.fu.slist[i + 3];
                float2 v4 = sh.fu.slist[i + 4], v5 = sh.fu.slist[i + 5];
                float2 v6 = sh.fu.slist[i + 6], v7 = sh.fu.slist[i + 7];
                acc0 += *(const float*)(xqb + (__float_as_int(v0.y) + lane4)) * v0.x;
                acc1 += *(const float*)(xqb + (__float_as_int(v1.y) + lane4)) * v1.x;
                acc2 += *(const float*)(xqb + (__float_as_int(v2.y) + lane4)) * v2.x;
                acc3 += *(const float*)(xqb + (__float_as_int(v3.y) + lane4)) * v3.x;
                acc0 += *(const float*)(xqb + (__float_as_int(v4.y) + lane4)) * v4.x;
                acc1 += *(const float*)(xqb + (__float_as_int(v5.y) + lane4)) * v5.x;
                acc2 += *(const float*)(xqb + (__float_as_int(v6.y) + lane4)) * v6.x;
                acc3 += *(const float*)(xqb + (__float_as_int(v7.y) + lane4)) * v7.x;
            }
            for (; i + 3 < b; i += 4) {
                float2 v0 = sh.fu.slist[i],     v1 = sh.fu.slist[i + 1];
                float2 v2 = sh.fu.slist[i + 2], v3 = sh.fu.slist[i + 3];
                acc0 += *(const float*)(xqb + (__float_as_int(v0.y) + lane4)) * v0.x;
                acc1 += *(const float*)(xqb + (__float_as_int(v1.y) + lane4)) * v1.x;
                acc2 += *(const float*)(xqb + (__float_as_int(v2.y) + lane4)) * v2.x;
                acc3 += *(const float*)(xqb + (__float_as_int(v3.y) + lane4)) * v3.x;
            }
            for (; i < b; ++i) {
                float2 v = sh.fu.slist[i];
                acc0 += *(const float*)(xqb + (__float_as_int(v.y) + lane4)) * v.x;
            }
            sh.fu.sxk[(r - rbase) * XSTR + lane] = (acc0 + acc1) + (acc2 + acc3);
        }
        __syncthreads();
        if (lane < 32) {
            const int kbase = ph ? 5 : 0;
            const int kcnt  = ph ? 4 : 5;
            for (int kk = 0; kk < kcnt; ++kk) {
                const float* xr = &sh.fu.sxk[(kk * 16 + nl) * XSTR + h * 32];
                const float* wp = &wT[((kbase + kk) * 8 + wv) * 128];   // uniform -> s_load
#pragma unroll
                for (int c4 = 0; c4 < 8; ++c4) {
                    float4 xv = *(const float4*)&xr[c4 * 4];
#pragma unroll
                    for (int cc = 0; cc < 4; ++cc) {
                        float xval = (&xv.x)[cc];
#pragma unroll
                        for (int j = 0; j < 4; ++j)
                            acc[j] += xval * wp[(c4 * 4 + cc) * 4 + j];
                    }
                }
            }
        }
        __syncthreads();
    }

    if (lane < 32) {
        const int n0 = (int)f * 16;
#pragma unroll
        for (int j = 0; j < 4; ++j) {
            int o = wv * 4 + j;
            out[((size_t)h * COUT + o) * N_OUT + n0 + nl] = acc[j] + bias[o];
        }
    }
}

// ---------------------------------------------------------------------------
extern "C" void kernel_launch(void* const* d_in, const int* in_sizes, int n_in,
                              void* d_out, int out_size, void* d_ws, size_t ws_size,
                              hipStream_t stream) {
    const float* x    = (const float*)d_in[0];
    const float* qw   = (const float*)d_in[1];
    const float* vals = (const float*)d_in[2];
    const float* w    = (const float*)d_in[3];
    const float* bias = (const float*)d_in[4];
    const int*   ik   = (const int*)d_in[5];
    const int*   io   = (const int*)d_in[6];
    const int*   ii   = (const int*)d_in[7];
    const int    nnz  = in_sizes[2];
    const int    nchA = (nnz + CHA - 1) / CHA;

    char* ws = (char*)d_ws;
    float*  xq    = (float*)ws;  ws += (size_t)N_IN * BC * 4;        // 4 MB
    float2* sivA  = (float2*)ws; ws += (size_t)NCB * ECAP_A * 8;     // 16.78 MB
    int*    gcntA = (int*)ws;    ws += NCB * 4;
    int*    done  = (int*)ws;    ws += 4;
    float*  wT    = (float*)ws;  ws += (size_t)COUT * CIN * KSZ * 4;

    hipMemsetAsync(gcntA, 0, (NCB + 1) * sizeof(int), stream);   // gcntA + done
    k_all<<<GRID, 512, 0, stream>>>(x, qw, vals, w, bias, ik, io, ii,
                                    xq, sivA, gcntA, done, wT,
                                    (float*)d_out, nnz, nchA);
}